// Round 6
// baseline (368.907 us; speedup 1.0000x reference)
//
#include <hip/hip_runtime.h>
#include <cstdint>

typedef unsigned short ushort_t;
typedef __attribute__((ext_vector_type(8))) short bf16x8;
typedef __attribute__((ext_vector_type(4))) float f32x4;

#define S_LEN 1024
#define DHEAD 64

__device__ inline ushort_t f2bf(float f) {
    union { float f; uint32_t u; } c; c.f = f;
    uint32_t u = c.u;
    uint32_t r = u + 0x7FFFu + ((u >> 16) & 1u);
    return (ushort_t)(r >> 16);
}
__device__ inline float bf2f(ushort_t h) {
    union { uint32_t u; float f; } c; c.u = ((uint32_t)h) << 16;
    return c.f;
}
__device__ inline bf16x8 load8(const ushort_t* p) {
    union { uint4 u; bf16x8 v; } c;
    c.u = *reinterpret_cast<const uint4*>(p);
    return c.v;
}

// ---------------------------------------------------------------------------
// prep_w: tiled transpose+convert 5 weights (512x512) fp32 -> bf16 W^T
// ---------------------------------------------------------------------------
__global__ __launch_bounds__(256) void prep_w(
    const float* __restrict__ wq, const float* __restrict__ wk,
    const float* __restrict__ wv, const float* __restrict__ wp,
    const float* __restrict__ wo, ushort_t* __restrict__ ws) {
    __shared__ float tile[64][65];
    int wi = blockIdx.z;
    const float* src = wi == 0 ? wq : wi == 1 ? wk : wi == 2 ? wv : wi == 3 ? wp : wo;
    int cx = blockIdx.x * 64, ry = blockIdx.y * 64;
    int t = threadIdx.x;
    int tr = t >> 4, tc = (t & 15) * 4;
#pragma unroll
    for (int i = 0; i < 4; i++) {
        int r = tr + i * 16;
        float4 f = *reinterpret_cast<const float4*>(src + (size_t)(ry + r) * 512 + cx + tc);
        tile[r][tc] = f.x; tile[r][tc + 1] = f.y; tile[r][tc + 2] = f.z; tile[r][tc + 3] = f.w;
    }
    __syncthreads();
    ushort_t* dst = ws + (size_t)wi * 262144;
#pragma unroll
    for (int i = 0; i < 4; i++) {
        int r = tr + i * 16;
        ushort4 o;
        o.x = f2bf(tile[tc][r]); o.y = f2bf(tile[tc + 1][r]);
        o.z = f2bf(tile[tc + 2][r]); o.w = f2bf(tile[tc + 3][r]);
        *reinterpret_cast<ushort4*>(dst + (size_t)(cx + r) * 512 + ry + tc) = o;
    }
}

// ---------------------------------------------------------------------------
// prep_act: elementwise fp32 -> bf16 for the 4 activations (8192x512 each)
// ---------------------------------------------------------------------------
__global__ __launch_bounds__(256) void prep_act(
    const float* __restrict__ q, const float* __restrict__ k,
    const float* __restrict__ v, const float* __restrict__ p,
    ushort_t* __restrict__ actb) {
    int t = blockIdx.x * 256 + threadIdx.x;   // 0..1048575
    int sec = blockIdx.y;
    const float* src = sec == 0 ? q : sec == 1 ? k : sec == 2 ? v : p;
    ushort_t* dst = actb + (size_t)sec * 4194304;
    float4 f = reinterpret_cast<const float4*>(src)[t];
    ushort4 o;
    o.x = f2bf(f.x); o.y = f2bf(f.y); o.z = f2bf(f.z); o.w = f2bf(f.w);
    *reinterpret_cast<ushort4*>(dst + (size_t)t * 4) = o;
}

// ---------------------------------------------------------------------------
// merged projection GEMM: z=0 Q (->Qu,Qv), z=1 K (->Kp), z=2 P (->Pp),
// z=3 V (->Vt transposed [bh][dh][s]). CVT=1: A fp32, convert during staging.
// CVT=0: A bf16 from pre-converted act buffer.
// ---------------------------------------------------------------------------
template<int CVT>
__global__ __launch_bounds__(256) void proj_gemm(
    const float* __restrict__ qa, const float* __restrict__ ka,
    const float* __restrict__ va, const float* __restrict__ pa,
    const ushort_t* __restrict__ actb,
    const ushort_t* __restrict__ wT,
    const float* __restrict__ bq, const float* __restrict__ bk,
    const float* __restrict__ bv,
    const float* __restrict__ ub, const float* __restrict__ vb,
    ushort_t* __restrict__ Qu, ushort_t* __restrict__ Qv,
    ushort_t* __restrict__ Kp, ushort_t* __restrict__ Pp,
    ushort_t* __restrict__ Vt) {
    __shared__ ushort_t smem[2][128][72];
    int z = blockIdx.z;
    const float* Af = z == 0 ? qa : z == 1 ? ka : z == 2 ? pa : va;
    const ushort_t* Ab = actb + (size_t)(z == 0 ? 0 : z == 1 ? 1 : z == 2 ? 3 : 2) * 4194304;
    const ushort_t* Bt = wT + (z == 0 ? 0 : z == 1 ? 262144 : z == 2 ? 786432 : 524288);
    const float* bias = z == 0 ? bq : z == 1 ? bk : z == 3 ? bv : nullptr;

    int tid = threadIdx.x;
    int wid = tid >> 6, lane = tid & 63, quad = lane >> 4, l16 = lane & 15;
    int wr = wid >> 1, wc = wid & 1;
    int row0 = blockIdx.y * 128, col0 = blockIdx.x * 128;

    f32x4 acc[4][4];
#pragma unroll
    for (int i = 0; i < 4; i++)
#pragma unroll
        for (int j = 0; j < 4; j++) acc[i][j] = (f32x4){0.f, 0.f, 0.f, 0.f};

    for (int k0 = 0; k0 < 512; k0 += 64) {
#pragma unroll
        for (int i = 0; i < 4; i++) {
            int cid = tid + i * 256;
            int r = cid >> 3, c8 = cid & 7;
            if (CVT) {
                const float* ap = Af + (size_t)(row0 + r) * 512 + k0 + c8 * 8;
                float4 f0 = *reinterpret_cast<const float4*>(ap);
                float4 f1 = *reinterpret_cast<const float4*>(ap + 4);
                union { ushort_t s[8]; uint4 u; } pk;
                pk.s[0] = f2bf(f0.x); pk.s[1] = f2bf(f0.y); pk.s[2] = f2bf(f0.z); pk.s[3] = f2bf(f0.w);
                pk.s[4] = f2bf(f1.x); pk.s[5] = f2bf(f1.y); pk.s[6] = f2bf(f1.z); pk.s[7] = f2bf(f1.w);
                *reinterpret_cast<uint4*>(&smem[0][r][c8 * 8]) = pk.u;
            } else {
                *reinterpret_cast<uint4*>(&smem[0][r][c8 * 8]) =
                    *reinterpret_cast<const uint4*>(Ab + (size_t)(row0 + r) * 512 + k0 + c8 * 8);
            }
            *reinterpret_cast<uint4*>(&smem[1][r][c8 * 8]) =
                *reinterpret_cast<const uint4*>(Bt + (size_t)(col0 + r) * 512 + k0 + c8 * 8);
        }
        __syncthreads();
#pragma unroll
        for (int kc = 0; kc < 2; kc++) {
            bf16x8 af[4], bg[4];
#pragma unroll
            for (int m = 0; m < 4; m++)
                af[m] = load8(&smem[0][wr * 64 + m * 16 + l16][kc * 32 + quad * 8]);
#pragma unroll
            for (int n = 0; n < 4; n++)
                bg[n] = load8(&smem[1][wc * 64 + n * 16 + l16][kc * 32 + quad * 8]);
#pragma unroll
            for (int m = 0; m < 4; m++)
#pragma unroll
                for (int n = 0; n < 4; n++)
                    acc[m][n] = __builtin_amdgcn_mfma_f32_16x16x32_bf16(af[m], bg[n], acc[m][n], 0, 0, 0);
        }
        __syncthreads();
    }

    if (z == 3) {
        ushort_t (*Ts)[130] = reinterpret_cast<ushort_t(*)[130]>(&smem[0][0][0]);
#pragma unroll
        for (int m = 0; m < 4; m++)
#pragma unroll
            for (int n = 0; n < 4; n++) {
                int dl = wc * 64 + n * 16 + l16;
                float bcol = bv[col0 + dl];
#pragma unroll
                for (int r = 0; r < 4; r++) {
                    int sl = wr * 64 + m * 16 + quad * 4 + r;
                    Ts[dl][sl] = f2bf(acc[m][n][r] + bcol);
                }
            }
        __syncthreads();
        int b_ = row0 >> 10, s0 = row0 & 1023;
#pragma unroll
        for (int p = 0; p < 8; p++) {
            int dl = p * 16 + (tid >> 4);
            int sl = (tid & 15) * 8;
            int col = col0 + dl, h_ = col >> 6, d_ = col & 63;
            ushort_t* dst = Vt + (((size_t)(b_ * 8 + h_)) * 64 + d_) * 1024 + s0 + sl;
            union { uint4 u; ushort_t s[8]; } pk;
#pragma unroll
            for (int e = 0; e < 8; e++) pk.s[e] = Ts[dl][sl + e];
            *reinterpret_cast<uint4*>(dst) = pk.u;
        }
    } else {
#pragma unroll
        for (int m = 0; m < 4; m++)
#pragma unroll
            for (int n = 0; n < 4; n++) {
                int col = col0 + wc * 64 + n * 16 + l16;
                float bcol = bias ? bias[col] : 0.f;
#pragma unroll
                for (int r = 0; r < 4; r++) {
                    int row = row0 + wr * 64 + m * 16 + quad * 4 + r;
                    float val = acc[m][n][r] + bcol;
                    int b_ = row >> 10, s_ = row & 1023, h_ = col >> 6, d_ = col & 63;
                    size_t idx = (((size_t)(b_ * 8 + h_)) * 1024 + s_) * 64 + d_;
                    if (z == 0) {
                        Qu[idx] = f2bf(val + ub[col]);
                        Qv[idx] = f2bf(val + vb[col]);
                    } else {
                        (z == 1 ? Kp : Pp)[idx] = f2bf(val);
                    }
                }
            }
    }
}

// ---------------------------------------------------------------------------
// out-proj: ctx[8192x512]bf16 @ Wo^T + bo -> fp32 out. 128x64 tiles, 512 blk.
// ---------------------------------------------------------------------------
__global__ __launch_bounds__(256) void out_gemm(
    const ushort_t* __restrict__ A, const ushort_t* __restrict__ Bt,
    const float* __restrict__ bias, float* __restrict__ outf) {
    __shared__ ushort_t As[128][72];
    __shared__ ushort_t Bs[64][72];
    int tid = threadIdx.x;
    int wid = tid >> 6, lane = tid & 63, quad = lane >> 4, l16 = lane & 15;
    int row0 = blockIdx.y * 128, col0 = blockIdx.x * 64;

    f32x4 acc[2][4];
#pragma unroll
    for (int i = 0; i < 2; i++)
#pragma unroll
        for (int j = 0; j < 4; j++) acc[i][j] = (f32x4){0.f, 0.f, 0.f, 0.f};

    for (int k0 = 0; k0 < 512; k0 += 64) {
#pragma unroll
        for (int i = 0; i < 4; i++) {
            int cid = tid + i * 256;
            int r = cid >> 3, c8 = cid & 7;
            *reinterpret_cast<uint4*>(&As[r][c8 * 8]) =
                *reinterpret_cast<const uint4*>(A + (size_t)(row0 + r) * 512 + k0 + c8 * 8);
        }
#pragma unroll
        for (int i = 0; i < 2; i++) {
            int cid = tid + i * 256;
            int r = cid >> 3, c8 = cid & 7;
            *reinterpret_cast<uint4*>(&Bs[r][c8 * 8]) =
                *reinterpret_cast<const uint4*>(Bt + (size_t)(col0 + r) * 512 + k0 + c8 * 8);
        }
        __syncthreads();
#pragma unroll
        for (int kc = 0; kc < 2; kc++) {
            bf16x8 af[2], bg[4];
#pragma unroll
            for (int m = 0; m < 2; m++)
                af[m] = load8(&As[wid * 32 + m * 16 + l16][kc * 32 + quad * 8]);
#pragma unroll
            for (int n = 0; n < 4; n++)
                bg[n] = load8(&Bs[n * 16 + l16][kc * 32 + quad * 8]);
#pragma unroll
            for (int m = 0; m < 2; m++)
#pragma unroll
                for (int n = 0; n < 4; n++)
                    acc[m][n] = __builtin_amdgcn_mfma_f32_16x16x32_bf16(af[m], bg[n], acc[m][n], 0, 0, 0);
        }
        __syncthreads();
    }
#pragma unroll
    for (int m = 0; m < 2; m++)
#pragma unroll
        for (int n = 0; n < 4; n++) {
            int col = col0 + n * 16 + l16;
#pragma unroll
            for (int r = 0; r < 4; r++) {
                int row = row0 + wid * 32 + m * 16 + quad * 4 + r;
                outf[(size_t)row * 512 + col] = acc[m][n][r] + bias[col];
            }
        }
}

// one pos window: 2 MFMA + sheared scatter-write (fast path when interior)
#define POS_EMIT(B0_, B1_, WT_) do {                                          \
    f32x4 acc_ = (f32x4){0.f, 0.f, 0.f, 0.f};                                 \
    acc_ = __builtin_amdgcn_mfma_f32_16x16x32_bf16(av[0], (B0_), acc_, 0, 0, 0); \
    acc_ = __builtin_amdgcn_mfma_f32_16x16x32_bf16(av[1], (B1_), acc_, 0, 0, 0); \
    int kb_ = (WT_) + kbb;                                                    \
    if (kb_ >= kw0 && kb_ + 30 < kw1 && (WT_) + 15 <= collim) {               \
        _Pragma("unroll") for (int r_ = 0; r_ < 4; r_++) {                    \
            int m_ = quad * 4 + r_;                                           \
            sc[m_][kb_ + m_ + l16] = f2bf(acc_[r_]);                          \
        }                                                                     \
    } else {                                                                  \
        _Pragma("unroll") for (int r_ = 0; r_ < 4; r_++) {                    \
            int m_ = quad * 4 + r_;                                           \
            int k_ = kb_ + m_ + l16;                                          \
            if (k_ >= kw0 && k_ < kw1 && ((WT_) + l16) <= collim)             \
                sc[m_][k_] = f2bf(acc_[r_]);                                  \
        }                                                                     \
    }                                                                         \
} while (0)

// ---------------------------------------------------------------------------
// pos window pass: unroll-by-2 software pipeline with NAMED register pairs
// (no dynamically-indexed register arrays). Use-then-reload = depth-2.
// ---------------------------------------------------------------------------
__device__ __forceinline__ void pos_pass(
    const ushort_t* __restrict__ P_b, ushort_t (*sc)[1032],
    const bf16x8* av, int wlo, int whi, int kbb, int collim,
    int kw0, int kw1, int quad, int l16) {
    if (whi < wlo) return;
    int nw = (whi - wlo) / 16 + 1;
    bf16x8 A0, A1, B0, B1;
    {
        int pr = wlo + l16; if (pr > S_LEN - 1) pr = S_LEN - 1;
        A0 = load8(P_b + (size_t)pr * 64 + quad * 8);
        A1 = load8(P_b + (size_t)pr * 64 + 32 + quad * 8);
    }
    if (nw > 1) {
        int pr = wlo + 16 + l16; if (pr > S_LEN - 1) pr = S_LEN - 1;
        B0 = load8(P_b + (size_t)pr * 64 + quad * 8);
        B1 = load8(P_b + (size_t)pr * 64 + 32 + quad * 8);
    }
    int w = 0;
    for (; w + 1 < nw; w += 2) {
        int wtA = wlo + w * 16;
        POS_EMIT(A0, A1, wtA);
        if (w + 2 < nw) {
            int pr = wtA + 32 + l16; if (pr > S_LEN - 1) pr = S_LEN - 1;
            A0 = load8(P_b + (size_t)pr * 64 + quad * 8);
            A1 = load8(P_b + (size_t)pr * 64 + 32 + quad * 8);
        }
        int wtB = wtA + 16;
        POS_EMIT(B0, B1, wtB);
        if (w + 3 < nw) {
            int pr = wtB + 32 + l16; if (pr > S_LEN - 1) pr = S_LEN - 1;
            B0 = load8(P_b + (size_t)pr * 64 + quad * 8);
            B1 = load8(P_b + (size_t)pr * 64 + 32 + quad * 8);
        }
    }
    if (w < nw) {
        int wt = wlo + w * 16;
        POS_EMIT(A0, A1, wt);
    }
}

// ---------------------------------------------------------------------------
// Fused attention v6: 16 q-rows/block (sc=33KB -> 4 blocks/CU, 16 waves/CU),
// 4 waves x 256-k, XCD-aware bh swizzle, named-var pipelined pos, unrolled
// content/PV. Doubled wave concurrency vs v5 attacks the L2-latency bound.
// ---------------------------------------------------------------------------
__global__ __launch_bounds__(256, 4) void attn_kernel(
    const ushort_t* __restrict__ Qu, const ushort_t* __restrict__ Qv,
    const ushort_t* __restrict__ Kp, const ushort_t* __restrict__ Pp,
    const ushort_t* __restrict__ Vt, ushort_t* __restrict__ ctxb) {
    __shared__ ushort_t sc[16][1032];   // 33 KB
    __shared__ float red1[4][16];
    __shared__ float red2[16][16];
    __shared__ float rowinv[16];

    constexpr float SCL = (float)(1.4426950408889634 / 22.627416997969522);

    // XCD swizzle: dispatch i -> XCD i%8; XCD j owns bh [8j, 8j+8) so its
    // K/P/V working set (~3MB) fits the 4MB per-XCD L2.
    int i = blockIdx.x;
    int bh = (i & 7) * 8 + (i >> 9);
    int q0 = ((i >> 3) & 63) << 4;

    int tid = threadIdx.x, wid = tid >> 6, lane = tid & 63;
    int quad = lane >> 4, l16 = lane & 15;

    const ushort_t* Qu_b = Qu + (size_t)bh * S_LEN * DHEAD;
    const ushort_t* Qv_b = Qv + (size_t)bh * S_LEN * DHEAD;
    const ushort_t* K_b  = Kp + (size_t)bh * S_LEN * DHEAD;
    const ushort_t* P_b  = Pp + (size_t)bh * S_LEN * DHEAD;
    const ushort_t* V_b  = Vt + (size_t)bh * DHEAD * S_LEN;

    int kw0 = wid << 8, kw1 = kw0 + 256;
    int d0 = wid << 4;

    bf16x8 au[2];
#pragma unroll
    for (int kc = 0; kc < 2; kc++)
        au[kc] = load8(Qu_b + (size_t)(q0 + l16) * 64 + kc * 32 + quad * 8);

    // zero-fill k = q+1 inside this wave's range
    if (lane < 16) {
        int kz = q0 + lane + 1;
        if (kz >= kw0 && kz < kw1) sc[lane][kz] = 0;
    }

    // ---- pos scores (partition of k: branch1 k<=q, branch2 k>=q+2) ----
    {
        bf16x8 av1[2], av2[2];
#pragma unroll
        for (int kc = 0; kc < 2; kc++) {
            av1[kc] = load8(Qv_b + (size_t)(q0 + l16) * 64 + kc * 32 + quad * 8);
            int r2 = q0 + 1 + l16; if (r2 > S_LEN - 1) r2 = S_LEN - 1;
            av2[kc] = load8(Qv_b + (size_t)r2 * 64 + kc * 32 + quad * 8);
        }
        int wlo = (S_LEN - 16) - q0 + kw0;
        int d1 = kw1 - 1 - q0; if (d1 > 0) d1 = 0;
        int whi = (S_LEN - 1) + d1;
        {
            const bf16x8* av = av1;
            pos_pass(P_b, sc, av, wlo, whi, q0 - (S_LEN - 1), S_LEN - 1,
                     kw0, kw1, quad, l16);
        }
        int wlo2 = kw0 - q0 - 17; if (wlo2 < 0) wlo2 = 0;
        int whi2 = kw1 - 3 - q0;
        {
            const bf16x8* av = av2;
            pos_pass(P_b, sc, av, wlo2, whi2, q0 + 2, 1 << 30,
                     kw0, kw1, quad, l16);
        }
    }

    // ---- content pass (fully unrolled; compiler hoists K loads) ----
    float pm[4] = {-1e30f, -1e30f, -1e30f, -1e30f};
    const ushort_t* Kw = K_b + (size_t)kw0 * 64;
#pragma unroll
    for (int nt = 0; nt < 16; ++nt) {
        const ushort_t* kp = Kw + (size_t)(nt * 16 + l16) * 64;
        bf16x8 b0 = load8(kp + quad * 8);
        bf16x8 b1 = load8(kp + 32 + quad * 8);
        int kt = kw0 + nt * 16;
        f32x4 a0;
#pragma unroll
        for (int r = 0; r < 4; r++) a0[r] = bf2f(sc[quad * 4 + r][kt + l16]);
        a0 = __builtin_amdgcn_mfma_f32_16x16x32_bf16(au[0], b0, a0, 0, 0, 0);
        a0 = __builtin_amdgcn_mfma_f32_16x16x32_bf16(au[1], b1, a0, 0, 0, 0);
#pragma unroll
        for (int r = 0; r < 4; r++) {
            sc[quad * 4 + r][kt + l16] = f2bf(a0[r]);
            pm[r] = fmaxf(pm[r], a0[r]);
        }
    }
#pragma unroll
    for (int off = 1; off < 16; off <<= 1)
#pragma unroll
        for (int r = 0; r < 4; r++) pm[r] = fmaxf(pm[r], __shfl_xor(pm[r], off));
    if (l16 == 0) {
#pragma unroll
        for (int r = 0; r < 4; r++) red1[wid][quad * 4 + r] = pm[r];
    }
    __syncthreads();   // B1

    // ---- softmax: thread (row=tid&15, cb=tid>>4) owns cols [cb*64,+64) ----
    int row = tid & 15, cb = tid >> 4;
    float rm = fmaxf(fmaxf(red1[0][row], red1[1][row]), fmaxf(red1[2][row], red1[3][row]));
    float ssum = 0.f;
    ushort_t* sp = &sc[row][cb * 64];
#pragma unroll
    for (int j = 0; j < 8; j++) {
        union { uint4 u; ushort_t s[8]; } in, out;
        in.u = *reinterpret_cast<uint4*>(sp + j * 8);
#pragma unroll
        for (int e = 0; e < 8; e++) {
            float ev = exp2f((bf2f(in.s[e]) - rm) * SCL);
            out.s[e] = f2bf(ev);
            ssum += ev;
        }
        *reinterpret_cast<uint4*>(sp + j * 8) = out.u;
    }
    red2[row][cb] = ssum;
    __syncthreads();   // B2
    if (tid < 16) {
        float s = 0.f;
#pragma unroll
        for (int c = 0; c < 16; c++) s += red2[tid][c];
        rowinv[tid] = 1.0f / s;
    }

    // ---- PV (fully unrolled; compiler hoists V loads) ----
    const ushort_t* Vw = V_b + (size_t)(d0 + l16) * 1024;
    f32x4 ac0 = (f32x4){0.f, 0.f, 0.f, 0.f};
#pragma unroll
    for (int kc = 0; kc < 32; ++kc) {
        bf16x8 b = load8(Vw + kc * 32 + quad * 8);
        bf16x8 a0 = load8(&sc[l16][kc * 32 + quad * 8]);
        ac0 = __builtin_amdgcn_mfma_f32_16x16x32_bf16(a0, b, ac0, 0, 0, 0);
    }
    __syncthreads();   // B3 (rowinv visibility)
    int b_ = bh >> 3, h_ = bh & 7;
#pragma unroll
    for (int r = 0; r < 4; r++) {
        int m = quad * 4 + r;
        ctxb[((size_t)b_ * 1024 + (q0 + m)) * 512 + h_ * 64 + d0 + l16] =
            f2bf(ac0[r] * rowinv[m]);
    }
}

extern "C" void kernel_launch(void* const* d_in, const int* in_sizes, int n_in,
                              void* d_out, int out_size, void* d_ws, size_t ws_size,
                              hipStream_t stream) {
    const float* q  = (const float*)d_in[0];
    const float* k  = (const float*)d_in[1];
    const float* v  = (const float*)d_in[2];
    const float* pe = (const float*)d_in[3];
    const float* Wq = (const float*)d_in[4];
    const float* bq = (const float*)d_in[5];
    const float* Wk = (const float*)d_in[6];
    const float* bk = (const float*)d_in[7];
    const float* Wv = (const float*)d_in[8];
    const float* bv = (const float*)d_in[9];
    const float* Wp = (const float*)d_in[10];
    const float* ub = (const float*)d_in[11];
    const float* vbias = (const float*)d_in[12];
    const float* Wo = (const float*)d_in[13];
    const float* bo = (const float*)d_in[14];
    float* out = (float*)d_out;
    ushort_t* ws = (ushort_t*)d_ws;

    ushort_t* wT  = ws;                       // 5 x 262144 = 1,310,720
    ushort_t* Qu  = ws + 1310720;
    ushort_t* Qv  = Qu + 4194304;
    ushort_t* Kp  = Qv + 4194304;
    ushort_t* Pp  = Kp + 4194304;
    ushort_t* Vt  = Pp + 4194304;
    ushort_t* actb = Vt + 4194304;            // big path: 4 x 4,194,304
    ushort_t* ctx_big = actb;                 // alias act[0]: dead after proj

    const size_t need_big = (size_t)(1310720 + 9 * 4194304) * 2;  // ~78.1 MB
    bool big = ws_size >= need_big;

    prep_w<<<dim3(8, 8, 5), 256, 0, stream>>>(Wq, Wk, Wv, Wp, Wo, wT);
    if (big) {
        prep_act<<<dim3(4096, 4), 256, 0, stream>>>(q, k, v, pe, actb);
        proj_gemm<0><<<dim3(4, 64, 4), 256, 0, stream>>>(q, k, v, pe, actb, wT,
            bq, bk, bv, ub, vbias, Qu, Qv, Kp, Pp, Vt);
        attn_kernel<<<4096, 256, 0, stream>>>(Qu, Qv, Kp, Pp, Vt, ctx_big);
        out_gemm<<<dim3(8, 64), 256, 0, stream>>>(ctx_big, wT + 4 * 262144, bo, out);
    } else {
        ushort_t* ctx = actb;
        proj_gemm<1><<<dim3(4, 64, 4), 256, 0, stream>>>(q, k, v, pe, nullptr, wT,
            bq, bk, bv, ub, vbias, Qu, Qv, Kp, Pp, Vt);
        attn_kernel<<<4096, 256, 0, stream>>>(Qu, Qv, Kp, Pp, Vt, ctx);
        out_gemm<<<dim3(8, 64), 256, 0, stream>>>(ctx, wT + 4 * 262144, bo, out);
    }
}

// Round 7
// 329.682 us; speedup vs baseline: 1.1190x; 1.1190x over previous
//
#include <hip/hip_runtime.h>
#include <cstdint>

typedef unsigned short ushort_t;
typedef __attribute__((ext_vector_type(8))) short bf16x8;
typedef __attribute__((ext_vector_type(4))) float f32x4;

#define S_LEN 1024
#define DHEAD 64

__device__ inline ushort_t f2bf(float f) {
    union { float f; uint32_t u; } c; c.f = f;
    uint32_t u = c.u;
    uint32_t r = u + 0x7FFFu + ((u >> 16) & 1u);
    return (ushort_t)(r >> 16);
}
__device__ inline float bf2f(ushort_t h) {
    union { uint32_t u; float f; } c; c.u = ((uint32_t)h) << 16;
    return c.f;
}
__device__ inline bf16x8 load8(const ushort_t* p) {
    union { uint4 u; bf16x8 v; } c;
    c.u = *reinterpret_cast<const uint4*>(p);
    return c.v;
}
// async global->LDS, 16B per lane; LDS dest = uniform base + lane*16
__device__ __forceinline__ void async16(const ushort_t* g, ushort_t* l) {
    __builtin_amdgcn_global_load_lds(
        (const __attribute__((address_space(1))) uint32_t*)(const void*)g,
        (__attribute__((address_space(3))) uint32_t*)(void*)l, 16, 0, 0);
}

// ---------------------------------------------------------------------------
// prep_w: tiled transpose+convert 5 weights (512x512) fp32 -> bf16 W^T
// ---------------------------------------------------------------------------
__global__ __launch_bounds__(256) void prep_w(
    const float* __restrict__ wq, const float* __restrict__ wk,
    const float* __restrict__ wv, const float* __restrict__ wp,
    const float* __restrict__ wo, ushort_t* __restrict__ ws) {
    __shared__ float tile[64][65];
    int wi = blockIdx.z;
    const float* src = wi == 0 ? wq : wi == 1 ? wk : wi == 2 ? wv : wi == 3 ? wp : wo;
    int cx = blockIdx.x * 64, ry = blockIdx.y * 64;
    int t = threadIdx.x;
    int tr = t >> 4, tc = (t & 15) * 4;
#pragma unroll
    for (int i = 0; i < 4; i++) {
        int r = tr + i * 16;
        float4 f = *reinterpret_cast<const float4*>(src + (size_t)(ry + r) * 512 + cx + tc);
        tile[r][tc] = f.x; tile[r][tc + 1] = f.y; tile[r][tc + 2] = f.z; tile[r][tc + 3] = f.w;
    }
    __syncthreads();
    ushort_t* dst = ws + (size_t)wi * 262144;
#pragma unroll
    for (int i = 0; i < 4; i++) {
        int r = tr + i * 16;
        ushort4 o;
        o.x = f2bf(tile[tc][r]); o.y = f2bf(tile[tc + 1][r]);
        o.z = f2bf(tile[tc + 2][r]); o.w = f2bf(tile[tc + 3][r]);
        *reinterpret_cast<ushort4*>(dst + (size_t)(cx + r) * 512 + ry + tc) = o;
    }
}

// ---------------------------------------------------------------------------
// prep_act: elementwise fp32 -> bf16 for the 4 activations (8192x512 each)
// ---------------------------------------------------------------------------
__global__ __launch_bounds__(256) void prep_act(
    const float* __restrict__ q, const float* __restrict__ k,
    const float* __restrict__ v, const float* __restrict__ p,
    ushort_t* __restrict__ actb) {
    int t = blockIdx.x * 256 + threadIdx.x;   // 0..1048575
    int sec = blockIdx.y;
    const float* src = sec == 0 ? q : sec == 1 ? k : sec == 2 ? v : p;
    ushort_t* dst = actb + (size_t)sec * 4194304;
    float4 f = reinterpret_cast<const float4*>(src)[t];
    ushort4 o;
    o.x = f2bf(f.x); o.y = f2bf(f.y); o.z = f2bf(f.z); o.w = f2bf(f.w);
    *reinterpret_cast<ushort4*>(dst + (size_t)t * 4) = o;
}

// ---------------------------------------------------------------------------
// proj_gemm (async): z=0 Q (->Qu,Qv), z=1 K (->Kp), z=2 P (->Pp),
// z=3 V (->Vt transposed). Staging via global_load_lds width=16 into
// UNPADDED [128][64] LDS (m97 pattern); wave w DMAs rows [32w,32w+32).
// ---------------------------------------------------------------------------
__global__ __launch_bounds__(256) void proj_gemm(
    const ushort_t* __restrict__ actb, const ushort_t* __restrict__ wT,
    const float* __restrict__ bq, const float* __restrict__ bk,
    const float* __restrict__ bv,
    const float* __restrict__ ub, const float* __restrict__ vb,
    ushort_t* __restrict__ Qu, ushort_t* __restrict__ Qv,
    ushort_t* __restrict__ Kp, ushort_t* __restrict__ Pp,
    ushort_t* __restrict__ Vt) {
    __shared__ ushort_t lds[16896];               // As 8192 + Bs 8192; Ts reuses all
    ushort_t (*As)[64] = (ushort_t(*)[64])lds;
    ushort_t (*Bs)[64] = (ushort_t(*)[64])(lds + 8192);

    int z = blockIdx.z;
    // act order: 0=q,1=k,2=v,3=p ; z order: 0=q,1=k,2=p,3=v
    const ushort_t* Ab = actb + (size_t)(z == 0 ? 0 : z == 1 ? 1 : z == 2 ? 3 : 2) * 4194304;
    const ushort_t* Bt = wT + (z == 0 ? 0 : z == 1 ? 262144 : z == 2 ? 786432 : 524288);
    const float* bias = z == 0 ? bq : z == 1 ? bk : z == 3 ? bv : nullptr;

    int tid = threadIdx.x;
    int wid = tid >> 6, lane = tid & 63, quad = lane >> 4, l16 = lane & 15;
    int wr = wid >> 1, wc = wid & 1;
    int row0 = blockIdx.y * 128, col0 = blockIdx.x * 128;

    f32x4 acc[4][4];
#pragma unroll
    for (int i = 0; i < 4; i++)
#pragma unroll
        for (int j = 0; j < 4; j++) acc[i][j] = (f32x4){0.f, 0.f, 0.f, 0.f};

    for (int k0 = 0; k0 < 512; k0 += 64) {
        // wave slab: rows [32*wid, +32) of A and B tiles; 4 async16 each
#pragma unroll
        for (int j = 0; j < 4; j++) {
            int idx = j * 64 + lane;              // 16B-chunk id in slab
            int r = 32 * wid + (idx >> 3);
            int c = (idx & 7) * 8;
            async16(Ab + (size_t)(row0 + r) * 512 + k0 + c,
                    &As[32 * wid][0] + j * 512);
            async16(Bt + (size_t)(col0 + r) * 512 + k0 + c,
                    &Bs[32 * wid][0] + j * 512);
        }
        __syncthreads();
#pragma unroll
        for (int kc = 0; kc < 2; kc++) {
            bf16x8 af[4], bg[4];
#pragma unroll
            for (int m = 0; m < 4; m++)
                af[m] = load8(&As[wr * 64 + m * 16 + l16][kc * 32 + quad * 8]);
#pragma unroll
            for (int n = 0; n < 4; n++)
                bg[n] = load8(&Bs[wc * 64 + n * 16 + l16][kc * 32 + quad * 8]);
#pragma unroll
            for (int m = 0; m < 4; m++)
#pragma unroll
                for (int n = 0; n < 4; n++)
                    acc[m][n] = __builtin_amdgcn_mfma_f32_16x16x32_bf16(af[m], bg[n], acc[m][n], 0, 0, 0);
        }
        __syncthreads();
    }

    if (z == 3) {
        ushort_t (*Ts)[130] = (ushort_t(*)[130])lds;   // 128*130=16640 <= 16896
#pragma unroll
        for (int m = 0; m < 4; m++)
#pragma unroll
            for (int n = 0; n < 4; n++) {
                int dl = wc * 64 + n * 16 + l16;
                float bcol = bv[col0 + dl];
#pragma unroll
                for (int r = 0; r < 4; r++) {
                    int sl = wr * 64 + m * 16 + quad * 4 + r;
                    Ts[dl][sl] = f2bf(acc[m][n][r] + bcol);
                }
            }
        __syncthreads();
        int b_ = row0 >> 10, s0 = row0 & 1023;
#pragma unroll
        for (int p = 0; p < 8; p++) {
            int dl = p * 16 + (tid >> 4);
            int sl = (tid & 15) * 8;
            int col = col0 + dl, h_ = col >> 6, d_ = col & 63;
            ushort_t* dst = Vt + (((size_t)(b_ * 8 + h_)) * 64 + d_) * 1024 + s0 + sl;
            union { uint4 u; ushort_t s[8]; } pk;
#pragma unroll
            for (int e = 0; e < 8; e++) pk.s[e] = Ts[dl][sl + e];
            *reinterpret_cast<uint4*>(dst) = pk.u;
        }
    } else {
#pragma unroll
        for (int m = 0; m < 4; m++)
#pragma unroll
            for (int n = 0; n < 4; n++) {
                int col = col0 + wc * 64 + n * 16 + l16;
                float bcol = bias ? bias[col] : 0.f;
#pragma unroll
                for (int r = 0; r < 4; r++) {
                    int row = row0 + wr * 64 + m * 16 + quad * 4 + r;
                    float val = acc[m][n][r] + bcol;
                    int b_ = row >> 10, s_ = row & 1023, h_ = col >> 6, d_ = col & 63;
                    size_t idx = (((size_t)(b_ * 8 + h_)) * 1024 + s_) * 64 + d_;
                    if (z == 0) {
                        Qu[idx] = f2bf(val + ub[col]);
                        Qv[idx] = f2bf(val + vb[col]);
                    } else {
                        (z == 1 ? Kp : Pp)[idx] = f2bf(val);
                    }
                }
            }
    }
}

// ---------------------------------------------------------------------------
// proj_gemm_cvt: fallback (small ws) — R5 padded staging with fp32 convert.
// ---------------------------------------------------------------------------
__global__ __launch_bounds__(256) void proj_gemm_cvt(
    const float* __restrict__ qa, const float* __restrict__ ka,
    const float* __restrict__ va, const float* __restrict__ pa,
    const ushort_t* __restrict__ wT,
    const float* __restrict__ bq, const float* __restrict__ bk,
    const float* __restrict__ bv,
    const float* __restrict__ ub, const float* __restrict__ vb,
    ushort_t* __restrict__ Qu, ushort_t* __restrict__ Qv,
    ushort_t* __restrict__ Kp, ushort_t* __restrict__ Pp,
    ushort_t* __restrict__ Vt) {
    __shared__ ushort_t smem[2][128][72];
    int z = blockIdx.z;
    const float* Af = z == 0 ? qa : z == 1 ? ka : z == 2 ? pa : va;
    const ushort_t* Bt = wT + (z == 0 ? 0 : z == 1 ? 262144 : z == 2 ? 786432 : 524288);
    const float* bias = z == 0 ? bq : z == 1 ? bk : z == 3 ? bv : nullptr;

    int tid = threadIdx.x;
    int wid = tid >> 6, lane = tid & 63, quad = lane >> 4, l16 = lane & 15;
    int wr = wid >> 1, wc = wid & 1;
    int row0 = blockIdx.y * 128, col0 = blockIdx.x * 128;

    f32x4 acc[4][4];
#pragma unroll
    for (int i = 0; i < 4; i++)
#pragma unroll
        for (int j = 0; j < 4; j++) acc[i][j] = (f32x4){0.f, 0.f, 0.f, 0.f};

    for (int k0 = 0; k0 < 512; k0 += 64) {
#pragma unroll
        for (int i = 0; i < 4; i++) {
            int cid = tid + i * 256;
            int r = cid >> 3, c8 = cid & 7;
            const float* ap = Af + (size_t)(row0 + r) * 512 + k0 + c8 * 8;
            float4 f0 = *reinterpret_cast<const float4*>(ap);
            float4 f1 = *reinterpret_cast<const float4*>(ap + 4);
            union { ushort_t s[8]; uint4 u; } pk;
            pk.s[0] = f2bf(f0.x); pk.s[1] = f2bf(f0.y); pk.s[2] = f2bf(f0.z); pk.s[3] = f2bf(f0.w);
            pk.s[4] = f2bf(f1.x); pk.s[5] = f2bf(f1.y); pk.s[6] = f2bf(f1.z); pk.s[7] = f2bf(f1.w);
            *reinterpret_cast<uint4*>(&smem[0][r][c8 * 8]) = pk.u;
            *reinterpret_cast<uint4*>(&smem[1][r][c8 * 8]) =
                *reinterpret_cast<const uint4*>(Bt + (size_t)(col0 + r) * 512 + k0 + c8 * 8);
        }
        __syncthreads();
#pragma unroll
        for (int kc = 0; kc < 2; kc++) {
            bf16x8 af[4], bg[4];
#pragma unroll
            for (int m = 0; m < 4; m++)
                af[m] = load8(&smem[0][wr * 64 + m * 16 + l16][kc * 32 + quad * 8]);
#pragma unroll
            for (int n = 0; n < 4; n++)
                bg[n] = load8(&smem[1][wc * 64 + n * 16 + l16][kc * 32 + quad * 8]);
#pragma unroll
            for (int m = 0; m < 4; m++)
#pragma unroll
                for (int n = 0; n < 4; n++)
                    acc[m][n] = __builtin_amdgcn_mfma_f32_16x16x32_bf16(af[m], bg[n], acc[m][n], 0, 0, 0);
        }
        __syncthreads();
    }

    if (z == 3) {
        ushort_t (*Ts)[130] = reinterpret_cast<ushort_t(*)[130]>(&smem[0][0][0]);
#pragma unroll
        for (int m = 0; m < 4; m++)
#pragma unroll
            for (int n = 0; n < 4; n++) {
                int dl = wc * 64 + n * 16 + l16;
                float bcol = bv[col0 + dl];
#pragma unroll
                for (int r = 0; r < 4; r++) {
                    int sl = wr * 64 + m * 16 + quad * 4 + r;
                    Ts[dl][sl] = f2bf(acc[m][n][r] + bcol);
                }
            }
        __syncthreads();
        int b_ = row0 >> 10, s0 = row0 & 1023;
#pragma unroll
        for (int p = 0; p < 8; p++) {
            int dl = p * 16 + (tid >> 4);
            int sl = (tid & 15) * 8;
            int col = col0 + dl, h_ = col >> 6, d_ = col & 63;
            ushort_t* dst = Vt + (((size_t)(b_ * 8 + h_)) * 64 + d_) * 1024 + s0 + sl;
            union { uint4 u; ushort_t s[8]; } pk;
#pragma unroll
            for (int e = 0; e < 8; e++) pk.s[e] = Ts[dl][sl + e];
            *reinterpret_cast<uint4*>(dst) = pk.u;
        }
    } else {
#pragma unroll
        for (int m = 0; m < 4; m++)
#pragma unroll
            for (int n = 0; n < 4; n++) {
                int col = col0 + wc * 64 + n * 16 + l16;
                float bcol = bias ? bias[col] : 0.f;
#pragma unroll
                for (int r = 0; r < 4; r++) {
                    int row = row0 + wr * 64 + m * 16 + quad * 4 + r;
                    float val = acc[m][n][r] + bcol;
                    int b_ = row >> 10, s_ = row & 1023, h_ = col >> 6, d_ = col & 63;
                    size_t idx = (((size_t)(b_ * 8 + h_)) * 1024 + s_) * 64 + d_;
                    if (z == 0) {
                        Qu[idx] = f2bf(val + ub[col]);
                        Qv[idx] = f2bf(val + vb[col]);
                    } else {
                        (z == 1 ? Kp : Pp)[idx] = f2bf(val);
                    }
                }
            }
    }
}

// ---------------------------------------------------------------------------
// out-proj (async): ctx[8192x512]bf16 @ Wo^T + bo -> fp32. 128x64 tiles.
// ---------------------------------------------------------------------------
__global__ __launch_bounds__(256) void out_gemm(
    const ushort_t* __restrict__ A, const ushort_t* __restrict__ Bt,
    const float* __restrict__ bias, float* __restrict__ outf) {
    __shared__ ushort_t As[128][64];
    __shared__ ushort_t Bs[64][64];
    int tid = threadIdx.x;
    int wid = tid >> 6, lane = tid & 63, quad = lane >> 4, l16 = lane & 15;
    int row0 = blockIdx.y * 128, col0 = blockIdx.x * 64;

    f32x4 acc[2][4];
#pragma unroll
    for (int i = 0; i < 2; i++)
#pragma unroll
        for (int j = 0; j < 4; j++) acc[i][j] = (f32x4){0.f, 0.f, 0.f, 0.f};

    for (int k0 = 0; k0 < 512; k0 += 64) {
#pragma unroll
        for (int j = 0; j < 4; j++) {
            int idx = j * 64 + lane;
            int r = 32 * wid + (idx >> 3);
            int c = (idx & 7) * 8;
            async16(A + (size_t)(row0 + r) * 512 + k0 + c, &As[32 * wid][0] + j * 512);
        }
#pragma unroll
        for (int j = 0; j < 2; j++) {
            int idx = j * 64 + lane;
            int r = 16 * wid + (idx >> 3);
            int c = (idx & 7) * 8;
            async16(Bt + (size_t)(col0 + r) * 512 + k0 + c, &Bs[16 * wid][0] + j * 512);
        }
        __syncthreads();
#pragma unroll
        for (int kc = 0; kc < 2; kc++) {
            bf16x8 af[2], bg[4];
#pragma unroll
            for (int m = 0; m < 2; m++)
                af[m] = load8(&As[wid * 32 + m * 16 + l16][kc * 32 + quad * 8]);
#pragma unroll
            for (int n = 0; n < 4; n++)
                bg[n] = load8(&Bs[n * 16 + l16][kc * 32 + quad * 8]);
#pragma unroll
            for (int m = 0; m < 2; m++)
#pragma unroll
                for (int n = 0; n < 4; n++)
                    acc[m][n] = __builtin_amdgcn_mfma_f32_16x16x32_bf16(af[m], bg[n], acc[m][n], 0, 0, 0);
        }
        __syncthreads();
    }
#pragma unroll
    for (int m = 0; m < 2; m++)
#pragma unroll
        for (int n = 0; n < 4; n++) {
            int col = col0 + n * 16 + l16;
#pragma unroll
            for (int r = 0; r < 4; r++) {
                int row = row0 + wid * 32 + m * 16 + quad * 4 + r;
                outf[(size_t)row * 512 + col] = acc[m][n][r] + bias[col];
            }
        }
}

// one pos window: 2 MFMA + sheared scatter-write (fast path when interior)
#define POS_EMIT(B0_, B1_, WT_) do {                                          \
    f32x4 acc_ = (f32x4){0.f, 0.f, 0.f, 0.f};                                 \
    acc_ = __builtin_amdgcn_mfma_f32_16x16x32_bf16(av[0], (B0_), acc_, 0, 0, 0); \
    acc_ = __builtin_amdgcn_mfma_f32_16x16x32_bf16(av[1], (B1_), acc_, 0, 0, 0); \
    int kb_ = (WT_) + kbb;                                                    \
    if (kb_ >= kw0 && kb_ + 30 < kw1 && (WT_) + 15 <= collim) {               \
        _Pragma("unroll") for (int r_ = 0; r_ < 4; r_++) {                    \
            int m_ = quad * 4 + r_;                                           \
            sc[mtrow + m_][kb_ + m_ + l16] = f2bf(acc_[r_]);                  \
        }                                                                     \
    } else {                                                                  \
        _Pragma("unroll") for (int r_ = 0; r_ < 4; r_++) {                    \
            int m_ = quad * 4 + r_;                                           \
            int k_ = kb_ + m_ + l16;                                          \
            if (k_ >= kw0 && k_ < kw1 && ((WT_) + l16) <= collim)             \
                sc[mtrow + m_][k_] = f2bf(acc_[r_]);                          \
        }                                                                     \
    }                                                                         \
} while (0)

// pos window pass: unroll-by-2 pipeline with NAMED register pairs
__device__ __forceinline__ void pos_pass(
    const ushort_t* __restrict__ P_b, ushort_t (*sc)[1032],
    const bf16x8* av, int wlo, int whi, int kbb, int collim, int mtrow,
    int kw0, int kw1, int quad, int l16) {
    if (whi < wlo) return;
    int nw = (whi - wlo) / 16 + 1;
    bf16x8 A0, A1, B0, B1;
    {
        int pr = wlo + l16; if (pr > S_LEN - 1) pr = S_LEN - 1;
        A0 = load8(P_b + (size_t)pr * 64 + quad * 8);
        A1 = load8(P_b + (size_t)pr * 64 + 32 + quad * 8);
    }
    if (nw > 1) {
        int pr = wlo + 16 + l16; if (pr > S_LEN - 1) pr = S_LEN - 1;
        B0 = load8(P_b + (size_t)pr * 64 + quad * 8);
        B1 = load8(P_b + (size_t)pr * 64 + 32 + quad * 8);
    }
    int w = 0;
    for (; w + 1 < nw; w += 2) {
        int wtA = wlo + w * 16;
        POS_EMIT(A0, A1, wtA);
        if (w + 2 < nw) {
            int pr = wtA + 32 + l16; if (pr > S_LEN - 1) pr = S_LEN - 1;
            A0 = load8(P_b + (size_t)pr * 64 + quad * 8);
            A1 = load8(P_b + (size_t)pr * 64 + 32 + quad * 8);
        }
        int wtB = wtA + 16;
        POS_EMIT(B0, B1, wtB);
        if (w + 3 < nw) {
            int pr = wtB + 32 + l16; if (pr > S_LEN - 1) pr = S_LEN - 1;
            B0 = load8(P_b + (size_t)pr * 64 + quad * 8);
            B1 = load8(P_b + (size_t)pr * 64 + 32 + quad * 8);
        }
    }
    if (w < nw) {
        int wt = wlo + w * 16;
        POS_EMIT(A0, A1, wt);
    }
}

// ---------------------------------------------------------------------------
// Fused attention (R5 exact): 32 q-rows/block, 4 waves x 256-k, XCD swizzle,
// named-var pipelined pos, fully-unrolled content/PV. Measured 152 us.
// ---------------------------------------------------------------------------
__global__ __launch_bounds__(256, 2) void attn_kernel(
    const ushort_t* __restrict__ Qu, const ushort_t* __restrict__ Qv,
    const ushort_t* __restrict__ Kp, const ushort_t* __restrict__ Pp,
    const ushort_t* __restrict__ Vt, ushort_t* __restrict__ ctxb) {
    __shared__ ushort_t sc[32][1032];
    __shared__ float red1[4][32];
    __shared__ float red2[32][8];
    __shared__ float rowinv[32];

    constexpr float SCL = (float)(1.4426950408889634 / 22.627416997969522);

    int i = blockIdx.x;
    int bh = (i & 7) * 8 + (i >> 8);
    int q0 = ((i >> 3) & 31) << 5;

    int tid = threadIdx.x, wid = tid >> 6, lane = tid & 63;
    int quad = lane >> 4, l16 = lane & 15;

    const ushort_t* Qu_b = Qu + (size_t)bh * S_LEN * DHEAD;
    const ushort_t* Qv_b = Qv + (size_t)bh * S_LEN * DHEAD;
    const ushort_t* K_b  = Kp + (size_t)bh * S_LEN * DHEAD;
    const ushort_t* P_b  = Pp + (size_t)bh * S_LEN * DHEAD;
    const ushort_t* V_b  = Vt + (size_t)bh * DHEAD * S_LEN;

    int kw0 = wid << 8, kw1 = kw0 + 256;
    int d0 = wid << 4;

    bf16x8 au0[2], au1[2];
#pragma unroll
    for (int kc = 0; kc < 2; kc++) {
        au0[kc] = load8(Qu_b + (size_t)(q0 + l16) * 64 + kc * 32 + quad * 8);
        au1[kc] = load8(Qu_b + (size_t)(q0 + 16 + l16) * 64 + kc * 32 + quad * 8);
    }

    if (lane < 32) {
        int kz = q0 + lane + 1;
        if (kz >= kw0 && kz < kw1) sc[lane][kz] = 0;
    }

#pragma unroll
    for (int mt = 0; mt < 2; mt++) {
        int q0m = q0 + mt * 16;
        bf16x8 av1[2], av2[2];
#pragma unroll
        for (int kc = 0; kc < 2; kc++) {
            av1[kc] = load8(Qv_b + (size_t)(q0m + l16) * 64 + kc * 32 + quad * 8);
            int r2 = q0m + 1 + l16; if (r2 > S_LEN - 1) r2 = S_LEN - 1;
            av2[kc] = load8(Qv_b + (size_t)r2 * 64 + kc * 32 + quad * 8);
        }
        int wlo = (S_LEN - 16) - q0m + kw0;
        int d1 = kw1 - 1 - q0m; if (d1 > 0) d1 = 0;
        int whi = (S_LEN - 1) + d1;
        pos_pass(P_b, sc, av1, wlo, whi, q0m - (S_LEN - 1), S_LEN - 1,
                 mt * 16, kw0, kw1, quad, l16);
        int wlo2 = kw0 - q0m - 17; if (wlo2 < 0) wlo2 = 0;
        int whi2 = kw1 - 3 - q0m;
        pos_pass(P_b, sc, av2, wlo2, whi2, q0m + 2, 1 << 30,
                 mt * 16, kw0, kw1, quad, l16);
    }

    float pm0[4] = {-1e30f, -1e30f, -1e30f, -1e30f};
    float pm1[4] = {-1e30f, -1e30f, -1e30f, -1e30f};
    const ushort_t* Kw = K_b + (size_t)kw0 * 64;
#pragma unroll
    for (int nt = 0; nt < 16; ++nt) {
        const ushort_t* kp = Kw + (size_t)(nt * 16 + l16) * 64;
        bf16x8 b0 = load8(kp + quad * 8);
        bf16x8 b1 = load8(kp + 32 + quad * 8);
        int kt = kw0 + nt * 16;
        f32x4 a0, a1;
#pragma unroll
        for (int r = 0; r < 4; r++) {
            a0[r] = bf2f(sc[quad * 4 + r][kt + l16]);
            a1[r] = bf2f(sc[16 + quad * 4 + r][kt + l16]);
        }
        a0 = __builtin_amdgcn_mfma_f32_16x16x32_bf16(au0[0], b0, a0, 0, 0, 0);
        a0 = __builtin_amdgcn_mfma_f32_16x16x32_bf16(au0[1], b1, a0, 0, 0, 0);
        a1 = __builtin_amdgcn_mfma_f32_16x16x32_bf16(au1[0], b0, a1, 0, 0, 0);
        a1 = __builtin_amdgcn_mfma_f32_16x16x32_bf16(au1[1], b1, a1, 0, 0, 0);
#pragma unroll
        for (int r = 0; r < 4; r++) {
            sc[quad * 4 + r][kt + l16] = f2bf(a0[r]);
            sc[16 + quad * 4 + r][kt + l16] = f2bf(a1[r]);
            pm0[r] = fmaxf(pm0[r], a0[r]);
            pm1[r] = fmaxf(pm1[r], a1[r]);
        }
    }
#pragma unroll
    for (int off = 1; off < 16; off <<= 1)
#pragma unroll
        for (int r = 0; r < 4; r++) {
            pm0[r] = fmaxf(pm0[r], __shfl_xor(pm0[r], off));
            pm1[r] = fmaxf(pm1[r], __shfl_xor(pm1[r], off));
        }
    if (l16 == 0) {
#pragma unroll
        for (int r = 0; r < 4; r++) {
            red1[wid][quad * 4 + r] = pm0[r];
            red1[wid][16 + quad * 4 + r] = pm1[r];
        }
    }
    __syncthreads();   // B1

    int row = tid & 31, cb = tid >> 5;
    float rm = fmaxf(fmaxf(red1[0][row], red1[1][row]), fmaxf(red1[2][row], red1[3][row]));
    float ssum = 0.f;
    ushort_t* sp = &sc[row][cb * 128];
#pragma unroll
    for (int j = 0; j < 16; j++) {
        union { uint4 u; ushort_t s[8]; } in, out;
        in.u = *reinterpret_cast<uint4*>(sp + j * 8);
#pragma unroll
        for (int e = 0; e < 8; e++) {
            float ev = exp2f((bf2f(in.s[e]) - rm) * SCL);
            out.s[e] = f2bf(ev);
            ssum += ev;
        }
        *reinterpret_cast<uint4*>(sp + j * 8) = out.u;
    }
    red2[row][cb] = ssum;
    __syncthreads();   // B2
    if (tid < 32) {
        float s = 0.f;
#pragma unroll
        for (int c = 0; c < 8; c++) s += red2[tid][c];
        rowinv[tid] = 1.0f / s;
    }

    const ushort_t* Vw = V_b + (size_t)(d0 + l16) * 1024;
    f32x4 ac0 = (f32x4){0.f, 0.f, 0.f, 0.f};
    f32x4 ac1 = (f32x4){0.f, 0.f, 0.f, 0.f};
#pragma unroll
    for (int kc = 0; kc < 32; ++kc) {
        bf16x8 b = load8(Vw + kc * 32 + quad * 8);
        bf16x8 a0 = load8(&sc[l16][kc * 32 + quad * 8]);
        bf16x8 a1 = load8(&sc[16 + l16][kc * 32 + quad * 8]);
        ac0 = __builtin_amdgcn_mfma_f32_16x16x32_bf16(a0, b, ac0, 0, 0, 0);
        ac1 = __builtin_amdgcn_mfma_f32_16x16x32_bf16(a1, b, ac1, 0, 0, 0);
    }
    __syncthreads();   // B3
    int b_ = bh >> 3, h_ = bh & 7;
#pragma unroll
    for (int r = 0; r < 4; r++) {
        int m = quad * 4 + r;
        ctxb[((size_t)b_ * 1024 + (q0 + m)) * 512 + h_ * 64 + d0 + l16] =
            f2bf(ac0[r] * rowinv[m]);
        ctxb[((size_t)b_ * 1024 + (q0 + 16 + m)) * 512 + h_ * 64 + d0 + l16] =
            f2bf(ac1[r] * rowinv[16 + m]);
    }
}

extern "C" void kernel_launch(void* const* d_in, const int* in_sizes, int n_in,
                              void* d_out, int out_size, void* d_ws, size_t ws_size,
                              hipStream_t stream) {
    const float* q  = (const float*)d_in[0];
    const float* k  = (const float*)d_in[1];
    const float* v  = (const float*)d_in[2];
    const float* pe = (const float*)d_in[3];
    const float* Wq = (const float*)d_in[4];
    const float* bq = (const float*)d_in[5];
    const float* Wk = (const float*)d_in[6];
    const float* bk = (const float*)d_in[7];
    const float* Wv = (const float*)d_in[8];
    const float* bv = (const float*)d_in[9];
    const float* Wp = (const float*)d_in[10];
    const float* ub = (const float*)d_in[11];
    const float* vbias = (const float*)d_in[12];
    const float* Wo = (const float*)d_in[13];
    const float* bo = (const float*)d_in[14];
    float* out = (float*)d_out;
    ushort_t* ws = (ushort_t*)d_ws;

    ushort_t* wT  = ws;                       // 5 x 262144 = 1,310,720
    ushort_t* Qu  = ws + 1310720;
    ushort_t* Qv  = Qu + 4194304;
    ushort_t* Kp  = Qv + 4194304;
    ushort_t* Pp  = Kp + 4194304;
    ushort_t* Vt  = Pp + 4194304;
    ushort_t* actb = Vt + 4194304;            // big path: 4 x 4,194,304
    ushort_t* ctx_big = actb;                 // alias act[0]: dead after proj

    const size_t need_big = (size_t)(1310720 + 9 * 4194304) * 2;  // ~78.1 MB
    bool big = ws_size >= need_big;

    prep_w<<<dim3(8, 8, 5), 256, 0, stream>>>(Wq, Wk, Wv, Wp, Wo, wT);
    if (big) {
        prep_act<<<dim3(4096, 4), 256, 0, stream>>>(q, k, v, pe, actb);
        proj_gemm<<<dim3(4, 64, 4), 256, 0, stream>>>(actb, wT,
            bq, bk, bv, ub, vbias, Qu, Qv, Kp, Pp, Vt);
        attn_kernel<<<2048, 256, 0, stream>>>(Qu, Qv, Kp, Pp, Vt, ctx_big);
        out_gemm<<<dim3(8, 64), 256, 0, stream>>>(ctx_big, wT + 4 * 262144, bo, out);
    } else {
        ushort_t* ctx = actb;
        proj_gemm_cvt<<<dim3(4, 64, 4), 256, 0, stream>>>(q, k, v, pe, wT,
            bq, bk, bv, ub, vbias, Qu, Qv, Kp, Pp, Vt);
        attn_kernel<<<2048, 256, 0, stream>>>(Qu, Qv, Kp, Pp, Vt, ctx);
        out_gemm<<<dim3(8, 64), 256, 0, stream>>>(ctx, wT + 4 * 262144, bo, out);
    }
}

// Round 8
// 323.543 us; speedup vs baseline: 1.1402x; 1.0190x over previous
//
#include <hip/hip_runtime.h>
#include <cstdint>

typedef unsigned short ushort_t;
typedef __attribute__((ext_vector_type(8))) short bf16x8;
typedef __attribute__((ext_vector_type(4))) float f32x4;

#define S_LEN 1024
#define DHEAD 64

__device__ inline ushort_t f2bf(float f) {
    union { float f; uint32_t u; } c; c.f = f;
    uint32_t u = c.u;
    uint32_t r = u + 0x7FFFu + ((u >> 16) & 1u);
    return (ushort_t)(r >> 16);
}
__device__ inline float bf2f(ushort_t h) {
    union { uint32_t u; float f; } c; c.u = ((uint32_t)h) << 16;
    return c.f;
}
__device__ inline bf16x8 load8(const ushort_t* p) {
    union { uint4 u; bf16x8 v; } c;
    c.u = *reinterpret_cast<const uint4*>(p);
    return c.v;
}
// async global->LDS, 16B per lane; LDS dest = uniform base + lane*16
__device__ __forceinline__ void async16(const ushort_t* g, ushort_t* l) {
    __builtin_amdgcn_global_load_lds(
        (const __attribute__((address_space(1))) uint32_t*)(const void*)g,
        (__attribute__((address_space(3))) uint32_t*)(void*)l, 16, 0, 0);
}

// ---------------------------------------------------------------------------
// prep_w: tiled transpose+convert 5 weights (512x512) fp32 -> bf16 W^T
// ---------------------------------------------------------------------------
__global__ __launch_bounds__(256) void prep_w(
    const float* __restrict__ wq, const float* __restrict__ wk,
    const float* __restrict__ wv, const float* __restrict__ wp,
    const float* __restrict__ wo, ushort_t* __restrict__ ws) {
    __shared__ float tile[64][65];
    int wi = blockIdx.z;
    const float* src = wi == 0 ? wq : wi == 1 ? wk : wi == 2 ? wv : wi == 3 ? wp : wo;
    int cx = blockIdx.x * 64, ry = blockIdx.y * 64;
    int t = threadIdx.x;
    int tr = t >> 4, tc = (t & 15) * 4;
#pragma unroll
    for (int i = 0; i < 4; i++) {
        int r = tr + i * 16;
        float4 f = *reinterpret_cast<const float4*>(src + (size_t)(ry + r) * 512 + cx + tc);
        tile[r][tc] = f.x; tile[r][tc + 1] = f.y; tile[r][tc + 2] = f.z; tile[r][tc + 3] = f.w;
    }
    __syncthreads();
    ushort_t* dst = ws + (size_t)wi * 262144;
#pragma unroll
    for (int i = 0; i < 4; i++) {
        int r = tr + i * 16;
        ushort4 o;
        o.x = f2bf(tile[tc][r]); o.y = f2bf(tile[tc + 1][r]);
        o.z = f2bf(tile[tc + 2][r]); o.w = f2bf(tile[tc + 3][r]);
        *reinterpret_cast<ushort4*>(dst + (size_t)(cx + r) * 512 + ry + tc) = o;
    }
}

// ---------------------------------------------------------------------------
// proj_gemm: z=0 Q (->Qu,Qv), z=1 K (->Kp), z=2 P (->Pp), z=3 V (->Vt
// transposed). A fp32, converted during LDS staging (R3-measured path).
// ---------------------------------------------------------------------------
__global__ __launch_bounds__(256) void proj_gemm(
    const float* __restrict__ qa, const float* __restrict__ ka,
    const float* __restrict__ va, const float* __restrict__ pa,
    const ushort_t* __restrict__ wT,
    const float* __restrict__ bq, const float* __restrict__ bk,
    const float* __restrict__ bv,
    const float* __restrict__ ub, const float* __restrict__ vb,
    ushort_t* __restrict__ Qu, ushort_t* __restrict__ Qv,
    ushort_t* __restrict__ Kp, ushort_t* __restrict__ Pp,
    ushort_t* __restrict__ Vt) {
    __shared__ ushort_t smem[2][128][72];
    int z = blockIdx.z;
    const float* Af = z == 0 ? qa : z == 1 ? ka : z == 2 ? pa : va;
    const ushort_t* Bt = wT + (z == 0 ? 0 : z == 1 ? 262144 : z == 2 ? 786432 : 524288);
    const float* bias = z == 0 ? bq : z == 1 ? bk : z == 3 ? bv : nullptr;

    int tid = threadIdx.x;
    int wid = tid >> 6, lane = tid & 63, quad = lane >> 4, l16 = lane & 15;
    int wr = wid >> 1, wc = wid & 1;
    int row0 = blockIdx.y * 128, col0 = blockIdx.x * 128;

    f32x4 acc[4][4];
#pragma unroll
    for (int i = 0; i < 4; i++)
#pragma unroll
        for (int j = 0; j < 4; j++) acc[i][j] = (f32x4){0.f, 0.f, 0.f, 0.f};

    for (int k0 = 0; k0 < 512; k0 += 64) {
#pragma unroll
        for (int i = 0; i < 4; i++) {
            int cid = tid + i * 256;
            int r = cid >> 3, c8 = cid & 7;
            const float* ap = Af + (size_t)(row0 + r) * 512 + k0 + c8 * 8;
            float4 f0 = *reinterpret_cast<const float4*>(ap);
            float4 f1 = *reinterpret_cast<const float4*>(ap + 4);
            union { ushort_t s[8]; uint4 u; } pk;
            pk.s[0] = f2bf(f0.x); pk.s[1] = f2bf(f0.y); pk.s[2] = f2bf(f0.z); pk.s[3] = f2bf(f0.w);
            pk.s[4] = f2bf(f1.x); pk.s[5] = f2bf(f1.y); pk.s[6] = f2bf(f1.z); pk.s[7] = f2bf(f1.w);
            *reinterpret_cast<uint4*>(&smem[0][r][c8 * 8]) = pk.u;
            *reinterpret_cast<uint4*>(&smem[1][r][c8 * 8]) =
                *reinterpret_cast<const uint4*>(Bt + (size_t)(col0 + r) * 512 + k0 + c8 * 8);
        }
        __syncthreads();
#pragma unroll
        for (int kc = 0; kc < 2; kc++) {
            bf16x8 af[4], bg[4];
#pragma unroll
            for (int m = 0; m < 4; m++)
                af[m] = load8(&smem[0][wr * 64 + m * 16 + l16][kc * 32 + quad * 8]);
#pragma unroll
            for (int n = 0; n < 4; n++)
                bg[n] = load8(&smem[1][wc * 64 + n * 16 + l16][kc * 32 + quad * 8]);
#pragma unroll
            for (int m = 0; m < 4; m++)
#pragma unroll
                for (int n = 0; n < 4; n++)
                    acc[m][n] = __builtin_amdgcn_mfma_f32_16x16x32_bf16(af[m], bg[n], acc[m][n], 0, 0, 0);
        }
        __syncthreads();
    }

    if (z == 3) {
        ushort_t (*Ts)[130] = reinterpret_cast<ushort_t(*)[130]>(&smem[0][0][0]);
#pragma unroll
        for (int m = 0; m < 4; m++)
#pragma unroll
            for (int n = 0; n < 4; n++) {
                int dl = wc * 64 + n * 16 + l16;
                float bcol = bv[col0 + dl];
#pragma unroll
                for (int r = 0; r < 4; r++) {
                    int sl = wr * 64 + m * 16 + quad * 4 + r;
                    Ts[dl][sl] = f2bf(acc[m][n][r] + bcol);
                }
            }
        __syncthreads();
        int b_ = row0 >> 10, s0 = row0 & 1023;
#pragma unroll
        for (int p = 0; p < 8; p++) {
            int dl = p * 16 + (tid >> 4);
            int sl = (tid & 15) * 8;
            int col = col0 + dl, h_ = col >> 6, d_ = col & 63;
            ushort_t* dst = Vt + (((size_t)(b_ * 8 + h_)) * 64 + d_) * 1024 + s0 + sl;
            union { uint4 u; ushort_t s[8]; } pk;
#pragma unroll
            for (int e = 0; e < 8; e++) pk.s[e] = Ts[dl][sl + e];
            *reinterpret_cast<uint4*>(dst) = pk.u;
        }
    } else {
#pragma unroll
        for (int m = 0; m < 4; m++)
#pragma unroll
            for (int n = 0; n < 4; n++) {
                int col = col0 + wc * 64 + n * 16 + l16;
                float bcol = bias ? bias[col] : 0.f;
#pragma unroll
                for (int r = 0; r < 4; r++) {
                    int row = row0 + wr * 64 + m * 16 + quad * 4 + r;
                    float val = acc[m][n][r] + bcol;
                    int b_ = row >> 10, s_ = row & 1023, h_ = col >> 6, d_ = col & 63;
                    size_t idx = (((size_t)(b_ * 8 + h_)) * 1024 + s_) * 64 + d_;
                    if (z == 0) {
                        Qu[idx] = f2bf(val + ub[col]);
                        Qv[idx] = f2bf(val + vb[col]);
                    } else {
                        (z == 1 ? Kp : Pp)[idx] = f2bf(val);
                    }
                }
            }
    }
}

// ---------------------------------------------------------------------------
// out-proj (async staging): ctx[8192x512]bf16 @ Wo^T + bo -> fp32.
// ---------------------------------------------------------------------------
__global__ __launch_bounds__(256) void out_gemm(
    const ushort_t* __restrict__ A, const ushort_t* __restrict__ Bt,
    const float* __restrict__ bias, float* __restrict__ outf) {
    __shared__ ushort_t As[128][64];
    __shared__ ushort_t Bs[64][64];
    int tid = threadIdx.x;
    int wid = tid >> 6, lane = tid & 63, quad = lane >> 4, l16 = lane & 15;
    int row0 = blockIdx.y * 128, col0 = blockIdx.x * 64;

    f32x4 acc[2][4];
#pragma unroll
    for (int i = 0; i < 2; i++)
#pragma unroll
        for (int j = 0; j < 4; j++) acc[i][j] = (f32x4){0.f, 0.f, 0.f, 0.f};

    for (int k0 = 0; k0 < 512; k0 += 64) {
#pragma unroll
        for (int j = 0; j < 4; j++) {
            int idx = j * 64 + lane;
            int r = 32 * wid + (idx >> 3);
            int c = (idx & 7) * 8;
            async16(A + (size_t)(row0 + r) * 512 + k0 + c, &As[32 * wid][0] + j * 512);
        }
#pragma unroll
        for (int j = 0; j < 2; j++) {
            int idx = j * 64 + lane;
            int r = 16 * wid + (idx >> 3);
            int c = (idx & 7) * 8;
            async16(Bt + (size_t)(col0 + r) * 512 + k0 + c, &Bs[16 * wid][0] + j * 512);
        }
        __syncthreads();
#pragma unroll
        for (int kc = 0; kc < 2; kc++) {
            bf16x8 af[2], bg[4];
#pragma unroll
            for (int m = 0; m < 2; m++)
                af[m] = load8(&As[wid * 32 + m * 16 + l16][kc * 32 + quad * 8]);
#pragma unroll
            for (int n = 0; n < 4; n++)
                bg[n] = load8(&Bs[n * 16 + l16][kc * 32 + quad * 8]);
#pragma unroll
            for (int m = 0; m < 2; m++)
#pragma unroll
                for (int n = 0; n < 4; n++)
                    acc[m][n] = __builtin_amdgcn_mfma_f32_16x16x32_bf16(af[m], bg[n], acc[m][n], 0, 0, 0);
        }
        __syncthreads();
    }
#pragma unroll
    for (int m = 0; m < 2; m++)
#pragma unroll
        for (int n = 0; n < 4; n++) {
            int col = col0 + n * 16 + l16;
#pragma unroll
            for (int r = 0; r < 4; r++) {
                int row = row0 + wid * 32 + m * 16 + quad * 4 + r;
                outf[(size_t)row * 512 + col] = acc[m][n][r] + bias[col];
            }
        }
}

// one pos window: 2 MFMA + sheared scatter-write (fast path when interior)
#define POS_EMIT(B0_, B1_, WT_) do {                                          \
    f32x4 acc_ = (f32x4){0.f, 0.f, 0.f, 0.f};                                 \
    acc_ = __builtin_amdgcn_mfma_f32_16x16x32_bf16(av[0], (B0_), acc_, 0, 0, 0); \
    acc_ = __builtin_amdgcn_mfma_f32_16x16x32_bf16(av[1], (B1_), acc_, 0, 0, 0); \
    int kb_ = (WT_) + kbb;                                                    \
    if (kb_ >= kw0 && kb_ + 30 < kw1 && (WT_) + 15 <= collim) {               \
        _Pragma("unroll") for (int r_ = 0; r_ < 4; r_++) {                    \
            int m_ = quad * 4 + r_;                                           \
            sc[mtrow + m_][kb_ + m_ + l16] = f2bf(acc_[r_]);                  \
        }                                                                     \
    } else {                                                                  \
        _Pragma("unroll") for (int r_ = 0; r_ < 4; r_++) {                    \
            int m_ = quad * 4 + r_;                                           \
            int k_ = kb_ + m_ + l16;                                          \
            if (k_ >= kw0 && k_ < kw1 && ((WT_) + l16) <= collim)             \
                sc[mtrow + m_][k_] = f2bf(acc_[r_]);                          \
        }                                                                     \
    }                                                                         \
} while (0)

// pos window pass: unroll-by-2 pipeline with NAMED register pairs
__device__ __forceinline__ void pos_pass(
    const ushort_t* __restrict__ P_b, ushort_t (*sc)[1032],
    const bf16x8* av, int wlo, int whi, int kbb, int collim, int mtrow,
    int kw0, int kw1, int quad, int l16) {
    if (whi < wlo) return;
    int nw = (whi - wlo) / 16 + 1;
    bf16x8 A0, A1, B0, B1;
    {
        int pr = wlo + l16; if (pr > S_LEN - 1) pr = S_LEN - 1;
        A0 = load8(P_b + (size_t)pr * 64 + quad * 8);
        A1 = load8(P_b + (size_t)pr * 64 + 32 + quad * 8);
    }
    if (nw > 1) {
        int pr = wlo + 16 + l16; if (pr > S_LEN - 1) pr = S_LEN - 1;
        B0 = load8(P_b + (size_t)pr * 64 + quad * 8);
        B1 = load8(P_b + (size_t)pr * 64 + 32 + quad * 8);
    }
    int w = 0;
    for (; w + 1 < nw; w += 2) {
        int wtA = wlo + w * 16;
        POS_EMIT(A0, A1, wtA);
        if (w + 2 < nw) {
            int pr = wtA + 32 + l16; if (pr > S_LEN - 1) pr = S_LEN - 1;
            A0 = load8(P_b + (size_t)pr * 64 + quad * 8);
            A1 = load8(P_b + (size_t)pr * 64 + 32 + quad * 8);
        }
        int wtB = wtA + 16;
        POS_EMIT(B0, B1, wtB);
        if (w + 3 < nw) {
            int pr = wtB + 32 + l16; if (pr > S_LEN - 1) pr = S_LEN - 1;
            B0 = load8(P_b + (size_t)pr * 64 + quad * 8);
            B1 = load8(P_b + (size_t)pr * 64 + 32 + quad * 8);
        }
    }
    if (w < nw) {
        int wt = wlo + w * 16;
        POS_EMIT(A0, A1, wt);
    }
}

// ---------------------------------------------------------------------------
// Fused attention v7: R5 structure + register-resident scores. Content accs
// stay in VGPRs (static-indexed, fully unrolled); softmax max/exp/sum on
// registers; only exp'd P goes to LDS (for PV A-operand). Removes the raw-
// score LDS round-trip and its bf16 conversions.
// ---------------------------------------------------------------------------
__global__ __launch_bounds__(256, 2) void attn_kernel(
    const ushort_t* __restrict__ Qu, const ushort_t* __restrict__ Qv,
    const ushort_t* __restrict__ Kp, const ushort_t* __restrict__ Pp,
    const ushort_t* __restrict__ Vt, ushort_t* __restrict__ ctxb) {
    __shared__ ushort_t sc[32][1032];
    __shared__ float red1[4][32];
    __shared__ float red2[4][32];
    __shared__ float rowinv[32];

    constexpr float SCL = (float)(1.4426950408889634 / 22.627416997969522);

    int i = blockIdx.x;
    int bh = (i & 7) * 8 + (i >> 8);
    int q0 = ((i >> 3) & 31) << 5;

    int tid = threadIdx.x, wid = tid >> 6, lane = tid & 63;
    int quad = lane >> 4, l16 = lane & 15;

    const ushort_t* Qu_b = Qu + (size_t)bh * S_LEN * DHEAD;
    const ushort_t* Qv_b = Qv + (size_t)bh * S_LEN * DHEAD;
    const ushort_t* K_b  = Kp + (size_t)bh * S_LEN * DHEAD;
    const ushort_t* P_b  = Pp + (size_t)bh * S_LEN * DHEAD;
    const ushort_t* V_b  = Vt + (size_t)bh * DHEAD * S_LEN;

    int kw0 = wid << 8, kw1 = kw0 + 256;
    int d0 = wid << 4;

    bf16x8 au0[2], au1[2];
#pragma unroll
    for (int kc = 0; kc < 2; kc++) {
        au0[kc] = load8(Qu_b + (size_t)(q0 + l16) * 64 + kc * 32 + quad * 8);
        au1[kc] = load8(Qu_b + (size_t)(q0 + 16 + l16) * 64 + kc * 32 + quad * 8);
    }

    if (lane < 32) {
        int kz = q0 + lane + 1;
        if (kz >= kw0 && kz < kw1) sc[lane][kz] = 0;
    }

    // ---- pos scores into sc (sheared scatter, partition of k) ----
#pragma unroll
    for (int mt = 0; mt < 2; mt++) {
        int q0m = q0 + mt * 16;
        bf16x8 av1[2], av2[2];
#pragma unroll
        for (int kc = 0; kc < 2; kc++) {
            av1[kc] = load8(Qv_b + (size_t)(q0m + l16) * 64 + kc * 32 + quad * 8);
            int r2 = q0m + 1 + l16; if (r2 > S_LEN - 1) r2 = S_LEN - 1;
            av2[kc] = load8(Qv_b + (size_t)r2 * 64 + kc * 32 + quad * 8);
        }
        int wlo = (S_LEN - 16) - q0m + kw0;
        int d1 = kw1 - 1 - q0m; if (d1 > 0) d1 = 0;
        int whi = (S_LEN - 1) + d1;
        pos_pass(P_b, sc, av1, wlo, whi, q0m - (S_LEN - 1), S_LEN - 1,
                 mt * 16, kw0, kw1, quad, l16);
        int wlo2 = kw0 - q0m - 17; if (wlo2 < 0) wlo2 = 0;
        int whi2 = kw1 - 3 - q0m;
        pos_pass(P_b, sc, av2, wlo2, whi2, q0m + 2, 1 << 30,
                 mt * 16, kw0, kw1, quad, l16);
    }

    // ---- content pass: C = pos from LDS; scores stay in registers ----
    f32x4 s0[16], s1[16];
    float pm0[4] = {-1e30f, -1e30f, -1e30f, -1e30f};
    float pm1[4] = {-1e30f, -1e30f, -1e30f, -1e30f};
    const ushort_t* Kw = K_b + (size_t)kw0 * 64;
#pragma unroll
    for (int nt = 0; nt < 16; ++nt) {
        const ushort_t* kp = Kw + (size_t)(nt * 16 + l16) * 64;
        bf16x8 b0 = load8(kp + quad * 8);
        bf16x8 b1 = load8(kp + 32 + quad * 8);
        int kt = kw0 + nt * 16;
        f32x4 a0, a1;
#pragma unroll
        for (int r = 0; r < 4; r++) {
            a0[r] = bf2f(sc[quad * 4 + r][kt + l16]);
            a1[r] = bf2f(sc[16 + quad * 4 + r][kt + l16]);
        }
        a0 = __builtin_amdgcn_mfma_f32_16x16x32_bf16(au0[0], b0, a0, 0, 0, 0);
        a0 = __builtin_amdgcn_mfma_f32_16x16x32_bf16(au0[1], b1, a0, 0, 0, 0);
        a1 = __builtin_amdgcn_mfma_f32_16x16x32_bf16(au1[0], b0, a1, 0, 0, 0);
        a1 = __builtin_amdgcn_mfma_f32_16x16x32_bf16(au1[1], b1, a1, 0, 0, 0);
        s0[nt] = a0;
        s1[nt] = a1;
#pragma unroll
        for (int r = 0; r < 4; r++) {
            pm0[r] = fmaxf(pm0[r], a0[r]);
            pm1[r] = fmaxf(pm1[r], a1[r]);
        }
    }
#pragma unroll
    for (int off = 1; off < 16; off <<= 1)
#pragma unroll
        for (int r = 0; r < 4; r++) {
            pm0[r] = fmaxf(pm0[r], __shfl_xor(pm0[r], off));
            pm1[r] = fmaxf(pm1[r], __shfl_xor(pm1[r], off));
        }
    if (l16 == 0) {
#pragma unroll
        for (int r = 0; r < 4; r++) {
            red1[wid][quad * 4 + r] = pm0[r];
            red1[wid][16 + quad * 4 + r] = pm1[r];
        }
    }
    __syncthreads();   // B1: global row max

    // ---- softmax on registers; write exp'd P (bf16) to sc ----
    float rm0[4], rm1[4], sm0[4], sm1[4];
#pragma unroll
    for (int r = 0; r < 4; r++) {
        int m = quad * 4 + r;
        rm0[r] = fmaxf(fmaxf(red1[0][m], red1[1][m]), fmaxf(red1[2][m], red1[3][m]));
        rm1[r] = fmaxf(fmaxf(red1[0][16 + m], red1[1][16 + m]),
                       fmaxf(red1[2][16 + m], red1[3][16 + m]));
        sm0[r] = 0.f; sm1[r] = 0.f;
    }
#pragma unroll
    for (int nt = 0; nt < 16; ++nt) {
        int kt = kw0 + nt * 16;
#pragma unroll
        for (int r = 0; r < 4; r++) {
            float e0 = exp2f((s0[nt][r] - rm0[r]) * SCL);
            float e1 = exp2f((s1[nt][r] - rm1[r]) * SCL);
            sm0[r] += e0; sm1[r] += e1;
            sc[quad * 4 + r][kt + l16] = f2bf(e0);
            sc[16 + quad * 4 + r][kt + l16] = f2bf(e1);
        }
    }
#pragma unroll
    for (int off = 1; off < 16; off <<= 1)
#pragma unroll
        for (int r = 0; r < 4; r++) {
            sm0[r] += __shfl_xor(sm0[r], off);
            sm1[r] += __shfl_xor(sm1[r], off);
        }
    if (l16 == 0) {
#pragma unroll
        for (int r = 0; r < 4; r++) {
            red2[wid][quad * 4 + r] = sm0[r];
            red2[wid][16 + quad * 4 + r] = sm1[r];
        }
    }
    __syncthreads();   // B2: P visible + partial sums
    if (tid < 32) {
        rowinv[tid] = 1.0f / (red2[0][tid] + red2[1][tid] + red2[2][tid] + red2[3][tid]);
    }

    // ---- PV (fully unrolled) ----
    const ushort_t* Vw = V_b + (size_t)(d0 + l16) * 1024;
    f32x4 ac0 = (f32x4){0.f, 0.f, 0.f, 0.f};
    f32x4 ac1 = (f32x4){0.f, 0.f, 0.f, 0.f};
#pragma unroll
    for (int kc = 0; kc < 32; ++kc) {
        bf16x8 b = load8(Vw + kc * 32 + quad * 8);
        bf16x8 a0 = load8(&sc[l16][kc * 32 + quad * 8]);
        bf16x8 a1 = load8(&sc[16 + l16][kc * 32 + quad * 8]);
        ac0 = __builtin_amdgcn_mfma_f32_16x16x32_bf16(a0, b, ac0, 0, 0, 0);
        ac1 = __builtin_amdgcn_mfma_f32_16x16x32_bf16(a1, b, ac1, 0, 0, 0);
    }
    __syncthreads();   // B3: rowinv visibility
    int b_ = bh >> 3, h_ = bh & 7;
#pragma unroll
    for (int r = 0; r < 4; r++) {
        int m = quad * 4 + r;
        ctxb[((size_t)b_ * 1024 + (q0 + m)) * 512 + h_ * 64 + d0 + l16] =
            f2bf(ac0[r] * rowinv[m]);
        ctxb[((size_t)b_ * 1024 + (q0 + 16 + m)) * 512 + h_ * 64 + d0 + l16] =
            f2bf(ac1[r] * rowinv[16 + m]);
    }
}

extern "C" void kernel_launch(void* const* d_in, const int* in_sizes, int n_in,
                              void* d_out, int out_size, void* d_ws, size_t ws_size,
                              hipStream_t stream) {
    const float* q  = (const float*)d_in[0];
    const float* k  = (const float*)d_in[1];
    const float* v  = (const float*)d_in[2];
    const float* pe = (const float*)d_in[3];
    const float* Wq = (const float*)d_in[4];
    const float* bq = (const float*)d_in[5];
    const float* Wk = (const float*)d_in[6];
    const float* bk = (const float*)d_in[7];
    const float* Wv = (const float*)d_in[8];
    const float* bv = (const float*)d_in[9];
    const float* Wp = (const float*)d_in[10];
    const float* ub = (const float*)d_in[11];
    const float* vbias = (const float*)d_in[12];
    const float* Wo = (const float*)d_in[13];
    const float* bo = (const float*)d_in[14];
    float* out = (float*)d_out;
    ushort_t* ws = (ushort_t*)d_ws;

    // ws map (ushort elems), ~53 MB total
    ushort_t* wT  = ws;                       // 5 x 262144 = 1,310,720
    ushort_t* Qu  = ws + 1310720;
    ushort_t* Qv  = Qu + 4194304;
    ushort_t* Kp  = Qv + 4194304;
    ushort_t* Pp  = Kp + 4194304;
    ushort_t* Vt  = Pp + 4194304;
    ushort_t* ctx = Vt + 4194304;

    prep_w<<<dim3(8, 8, 5), 256, 0, stream>>>(Wq, Wk, Wv, Wp, Wo, wT);
    proj_gemm<<<dim3(4, 64, 4), 256, 0, stream>>>(q, k, v, pe, wT,
        bq, bk, bv, ub, vbias, Qu, Qv, Kp, Pp, Vt);
    attn_kernel<<<2048, 256, 0, stream>>>(Qu, Qv, Kp, Pp, Vt, ctx);
    out_gemm<<<dim3(8, 64), 256, 0, stream>>>(ctx, wT + 4 * 262144, bo, out);
}